// Round 5
// baseline (306.543 us; speedup 1.0000x reference)
//
#include <hip/hip_runtime.h>
#include <hip/hip_bf16.h>

typedef unsigned short ushort_t;

#define B_ 64
#define S_ 512
#define E_ 256
#define H_ 128
#define M_ (B_ * S_)   // 32768 rows
#define CAP_ 128       // max neighbor slots (nnz ~ Binom(512,0.05): mean 25.6, max ~55)

// Y (GEMM output / agg input) lives in CHUNKED layout: [b][chunk=col/32][512][32]
// h (agg output / GEMM input) lives in ROW-MAJOR layout: [row][128]

// ---------------------------------------------------------------------------
// K1: neighbor lists from binary adj (float4 reads) + invdeg = 1/(nnz+1)
// ---------------------------------------------------------------------------
__global__ void k_adjidx(const float* __restrict__ adj,
                         ushort_t* __restrict__ idxl,
                         int* __restrict__ nnz,
                         float* __restrict__ invdeg) {
    int row  = blockIdx.x * 4 + (threadIdx.x >> 6);
    int lane = threadIdx.x & 63;
    const float4* arow = (const float4*)(adj + (size_t)row * S_);
    ushort_t* dst = idxl + (size_t)row * CAP_;
    int total = 0;
    #pragma unroll
    for (int c = 0; c < 2; ++c) {
        float4 v = arow[c * 64 + lane];
        float f[4] = {v.x, v.y, v.z, v.w};
        #pragma unroll
        for (int j = 0; j < 4; ++j) {
            unsigned long long m = __ballot(f[j] != 0.0f);
            if (f[j] != 0.0f) {
                int pos = total + __popcll(m & ((1ull << lane) - 1ull));
                if (pos < CAP_) dst[pos] = (ushort_t)(c * 256 + lane * 4 + j);
            }
            total += __popcll(m);
        }
    }
    if (lane == 0) {
        nnz[row] = total < CAP_ ? total : CAP_;
        invdeg[row] = 1.0f / (float)(total + 1);
    }
}

// ---------------------------------------------------------------------------
// K2: barrier-free GEMM  Y[row, colBase:+64] (+)= X[row, kBase:+128] @ W^T
// BM=128 (4 waves x 32 rows), BN=64, KTILE=128. W slab in LDS (one barrier);
// each wave streams its private X rows through a per-wave LDS slab (no
// further barriers; same-wave DS ordering). Output written CHUNKED.
// ---------------------------------------------------------------------------
template <int WSTRIDE, int XSTRIDE, bool GATHER, bool ADD>
__global__ __launch_bounds__(256, 2) void k_gemm(const float* __restrict__ X,
                                                 const int* __restrict__ sent,
                                                 const float* __restrict__ emb,
                                                 const float* __restrict__ W,
                                                 int kBase,
                                                 float* __restrict__ out) {
    __shared__ float Ws[128][68];    // [k][j]  (34816 B)
    __shared__ float Xs[4][16][36];  // per-wave [k][row32] (9216 B)
    int tid  = threadIdx.x;
    int wave = tid >> 6, lane = tid & 63;
    int rb       = blockIdx.x >> 1;
    int colBase  = (blockIdx.x & 1) * 64;
    int rowBase  = rb * 128 + wave * 32;

    {   // one-time W slab preload (transpose to k-major)
        int j  = tid & 63;
        int kq = tid >> 6;
        const float* wp = W + (size_t)(colBase + j) * WSTRIDE + kBase + kq * 32;
        #pragma unroll
        for (int i = 0; i < 8; ++i) {
            float4 v = *(const float4*)(wp + i * 4);
            int k = kq * 32 + i * 4;
            Ws[k + 0][j] = v.x; Ws[k + 1][j] = v.y;
            Ws[k + 2][j] = v.z; Ws[k + 3][j] = v.w;
        }
    }

    int cc = lane & 15, rr = lane >> 4;    // micro-tile: 8 rows x 4 cols
    int kg = lane & 3,  rowi = lane >> 2;  // staging: rows (rowi, rowi+16), k-group kg

    const float* xs0;
    const float* xs1;
    if (GATHER) {
        xs0 = emb + (size_t)sent[rowBase + rowi]      * XSTRIDE + kBase + kg * 4;
        xs1 = emb + (size_t)sent[rowBase + rowi + 16] * XSTRIDE + kBase + kg * 4;
    } else {
        xs0 = X + (size_t)(rowBase + rowi)      * XSTRIDE + kBase + kg * 4;
        xs1 = X + (size_t)(rowBase + rowi + 16) * XSTRIDE + kBase + kg * 4;
    }
    float4 f0 = *(const float4*)(xs0);
    float4 f1 = *(const float4*)(xs1);

    __syncthreads();                       // Ws ready; the ONLY barrier

    float acc[8][4] = {};
    float (*xsw)[36] = Xs[wave];

    #pragma unroll 1
    for (int kk = 0; kk < 128; kk += 16) {
        xsw[kg * 4 + 0][rowi] = f0.x; xsw[kg * 4 + 1][rowi] = f0.y;
        xsw[kg * 4 + 2][rowi] = f0.z; xsw[kg * 4 + 3][rowi] = f0.w;
        xsw[kg * 4 + 0][rowi + 16] = f1.x; xsw[kg * 4 + 1][rowi + 16] = f1.y;
        xsw[kg * 4 + 2][rowi + 16] = f1.z; xsw[kg * 4 + 3][rowi + 16] = f1.w;
        if (kk + 16 < 128) {
            f0 = *(const float4*)(xs0 + kk + 16);
            f1 = *(const float4*)(xs1 + kk + 16);
        }
        #pragma unroll
        for (int k = 0; k < 16; ++k) {
            float4 x0 = *(const float4*)&xsw[k][rr * 8];
            float4 x1 = *(const float4*)&xsw[k][rr * 8 + 4];
            float4 wv = *(const float4*)&Ws[kk + k][cc * 4];
            float xv[8] = {x0.x, x0.y, x0.z, x0.w, x1.x, x1.y, x1.z, x1.w};
            #pragma unroll
            for (int i = 0; i < 8; ++i) {
                acc[i][0] += xv[i] * wv.x;
                acc[i][1] += xv[i] * wv.y;
                acc[i][2] += xv[i] * wv.z;
                acc[i][3] += xv[i] * wv.w;
            }
        }
    }

    int col   = colBase + cc * 4;
    int chunk = col >> 5, jc = col & 31;
    #pragma unroll
    for (int i = 0; i < 8; ++i) {
        int row = rowBase + rr * 8 + i;
        int bb  = row >> 9, r = row & 511;
        float* op = out + (((size_t)bb * 4 + chunk) * 512 + r) * 32 + jc;
        float4 o = {acc[i][0], acc[i][1], acc[i][2], acc[i][3]};
        if (ADD) {
            float4 p = *(const float4*)op;
            o.x += p.x; o.y += p.y; o.z += p.z; o.w += p.w;
        }
        *(float4*)op = o;
    }
}

// ---------------------------------------------------------------------------
// K3: LDS-slab aggregate + epilogue. One block per (batch, 32-col chunk):
// loads the 512x32 Y slab (64 KB) coalesced ONCE, then all neighbor gathers
// hit LDS. 512 threads = 64 row-groups x 8 float4-lanes; 8 rows per group.
//   h[row] = relu( (Y[row] + sum_{t in nbr(row)} Y[b,t] + 2b) * invdeg[row] )
// POOL: max over all 512 rows -> pooled[b][chunk*32..+32] directly.
// ---------------------------------------------------------------------------
template <bool POOL>
__global__ __launch_bounds__(512) void k_aggf(const float* __restrict__ Y,
                                              const ushort_t* __restrict__ idxl,
                                              const int* __restrict__ nnz,
                                              const float* __restrict__ invdeg,
                                              const float* __restrict__ bias,
                                              float* __restrict__ out) {
    __shared__ float slab[512 * 32];       // 65536 B
    float4* s4 = (float4*)slab;
    int b = blockIdx.x >> 2, chunk = blockIdx.x & 3;

    const float4* g4 = (const float4*)(Y + (((size_t)b * 4 + chunk) * 512) * 32);
    #pragma unroll
    for (int i = 0; i < 8; ++i) s4[threadIdx.x + i * 512] = g4[threadIdx.x + i * 512];
    __syncthreads();

    int lane = threadIdx.x & 63, wave = threadIdx.x >> 6;
    int grp  = wave * 8 + (lane >> 3);     // 0..63
    int j    = lane & 7;                   // float4 column within chunk
    float4 bv = ((const float4*)bias)[chunk * 8 + j];
    bv.x *= 2.0f; bv.y *= 2.0f; bv.z *= 2.0f; bv.w *= 2.0f;

    float4 vmax = {-1e30f, -1e30f, -1e30f, -1e30f};

    #pragma unroll 1
    for (int i = 0; i < 8; ++i) {
        int r   = grp * 8 + i;
        int row = b * S_ + r;
        int n = nnz[row];
        const ushort_t* il = idxl + (size_t)row * CAP_;
        float4 acc = s4[r * 8 + j];
        float4 acc2 = {0.f, 0.f, 0.f, 0.f};
        int q = 0;
        for (; q + 4 <= n; q += 4) {
            int t0 = il[q], t1 = il[q + 1], t2 = il[q + 2], t3 = il[q + 3];
            float4 v0 = s4[t0 * 8 + j];
            float4 v1 = s4[t1 * 8 + j];
            float4 v2 = s4[t2 * 8 + j];
            float4 v3 = s4[t3 * 8 + j];
            acc.x += v0.x + v1.x; acc.y += v0.y + v1.y;
            acc.z += v0.z + v1.z; acc.w += v0.w + v1.w;
            acc2.x += v2.x + v3.x; acc2.y += v2.y + v3.y;
            acc2.z += v2.z + v3.z; acc2.w += v2.w + v3.w;
        }
        for (; q < n; ++q) {
            float4 v = s4[il[q] * 8 + j];
            acc.x += v.x; acc.y += v.y; acc.z += v.z; acc.w += v.w;
        }
        acc.x += acc2.x; acc.y += acc2.y; acc.z += acc2.z; acc.w += acc2.w;

        float inv = invdeg[row];
        float4 o;
        o.x = fmaxf((acc.x + bv.x) * inv, 0.0f);
        o.y = fmaxf((acc.y + bv.y) * inv, 0.0f);
        o.z = fmaxf((acc.z + bv.z) * inv, 0.0f);
        o.w = fmaxf((acc.w + bv.w) * inv, 0.0f);

        if (!POOL) {
            *(float4*)(out + (size_t)row * H_ + chunk * 32 + j * 4) = o;
        } else {
            vmax.x = fmaxf(vmax.x, o.x); vmax.y = fmaxf(vmax.y, o.y);
            vmax.z = fmaxf(vmax.z, o.z); vmax.w = fmaxf(vmax.w, o.w);
        }
    }

    if (POOL) {
        __syncthreads();                   // all gathers done; slab reusable
        s4[grp * 8 + j] = vmax;            // 64 partials x 8 float4
        __syncthreads();
        if (threadIdx.x < 32) {
            int c = threadIdx.x;
            float m = -1e30f;
            #pragma unroll 8
            for (int g = 0; g < 64; ++g) m = fmaxf(m, slab[g * 32 + c]);
            out[(size_t)b * H_ + chunk * 32 + c] = m;
        }
    }
}

// ---------------------------------------------------------------------------
// K4: logits[b,c] = pooled[b,:] . Wp[c,:] + bp[c]   (pooled is [64][128])
// ---------------------------------------------------------------------------
__global__ void k_final(const float* __restrict__ pooled,
                        const float* __restrict__ Wp,
                        const float* __restrict__ bp,
                        float* __restrict__ out) {
    int b = blockIdx.x, j = threadIdx.x;  // 128 threads
    float m = pooled[(size_t)b * H_ + j];
    float t0 = m * Wp[j];
    float t1 = m * Wp[H_ + j];
    #pragma unroll
    for (int off = 32; off > 0; off >>= 1) {
        t0 += __shfl_down(t0, off);
        t1 += __shfl_down(t1, off);
    }
    __shared__ float red[2][2];
    int wave = j >> 6, lane = j & 63;
    if (lane == 0) { red[0][wave] = t0; red[1][wave] = t1; }
    __syncthreads();
    if (j == 0) out[b * 2 + 0] = red[0][0] + red[0][1] + bp[0];
    if (j == 1) out[b * 2 + 1] = red[1][0] + red[1][1] + bp[1];
}

// ---------------------------------------------------------------------------
extern "C" void kernel_launch(void* const* d_in, const int* in_sizes, int n_in,
                              void* d_out, int out_size, void* d_ws, size_t ws_size,
                              hipStream_t stream) {
    const int*   sent = (const int*)d_in[0];
    const float* adj  = (const float*)d_in[1];
    const float* emb  = (const float*)d_in[2];
    const float* W1   = (const float*)d_in[3];
    const float* b1   = (const float*)d_in[4];
    const float* W2   = (const float*)d_in[5];
    const float* b2   = (const float*)d_in[6];
    const float* W3   = (const float*)d_in[7];
    const float* b3   = (const float*)d_in[8];
    const float* Wp   = (const float*)d_in[9];
    const float* bp   = (const float*)d_in[10];
    float* out = (float*)d_out;

    char* ws = (char*)d_ws;
    float*    bufA   = (float*)ws;                                  // Y, chunked, M*128 f32
    float*    bufB   = (float*)(ws + (size_t)M_ * 256 * 4);         // h, row-major, M*128 f32
    float*    invdeg = (float*)(ws + (size_t)M_ * 512 * 4);         // M f32
    int*      nnz    = (int*)(ws + (size_t)M_ * 512 * 4 + M_ * 4);
    ushort_t* idxl   = (ushort_t*)(ws + (size_t)M_ * 512 * 4 + M_ * 8);          // M*CAP u16
    float*    pooled = (float*)(ws + (size_t)M_ * 512 * 4 + M_ * 8 + (size_t)M_ * CAP_ * 2);  // 64*128 f32

    k_adjidx<<<M_ / 4, 256, 0, stream>>>(adj, idxl, nnz, invdeg);

    // layer 1: Y1 = emb[sent] @ W1^T  — split-K (2 x KTILE=128), fused gather
    k_gemm<E_, E_, true, false><<<512, 256, 0, stream>>>(nullptr, sent, emb, W1, 0,   bufA);
    k_gemm<E_, E_, true, true ><<<512, 256, 0, stream>>>(nullptr, sent, emb, W1, 128, bufA);
    k_aggf<false><<<B_ * 4, 512, 0, stream>>>(bufA, idxl, nnz, invdeg, b1, bufB);

    // layer 2
    k_gemm<H_, H_, false, false><<<512, 256, 0, stream>>>(bufB, nullptr, nullptr, W2, 0, bufA);
    k_aggf<false><<<B_ * 4, 512, 0, stream>>>(bufA, idxl, nnz, invdeg, b2, bufB);

    // layer 3: agg + fused full max-pool (h3 never materialized)
    k_gemm<H_, H_, false, false><<<512, 256, 0, stream>>>(bufB, nullptr, nullptr, W3, 0, bufA);
    k_aggf<true><<<B_ * 4, 512, 0, stream>>>(bufA, idxl, nnz, invdeg, b3, pooled);

    k_final<<<B_, H_, 0, stream>>>(pooled, Wp, bp, out);
}